// Round 5
// baseline (1638.511 us; speedup 1.0000x reference)
//
#include <hip/hip_runtime.h>
#include <stdint.h>

typedef unsigned short u16;
typedef __attribute__((ext_vector_type(8))) __bf16 bf16x8;
typedef __attribute__((ext_vector_type(8))) u16 u16x8;
typedef __attribute__((ext_vector_type(4))) float f32x4;

#define TTS 256
#define NSEG 1024
#define TC 32            // time-chunk for gates

__device__ __forceinline__ u16 f2bf(float f) {
  union { float f; uint32_t u; } v; v.f = f;
  uint32_t r = v.u + 0x7fffu + ((v.u >> 16) & 1u);
  return (u16)(r >> 16);
}
__device__ __forceinline__ float bf2f(u16 h) {
  union { uint32_t u; float f; } v; v.u = ((uint32_t)h) << 16;
  return v.f;
}
__device__ __forceinline__ float sigm(float x) {
  return __builtin_amdgcn_rcpf(1.0f + __expf(-x));
}
// async global->LDS, 16B per lane; LDS dest must be wave-uniform base + lane*16
__device__ __forceinline__ void gl16(const void* g, void* l) {
  __builtin_amdgcn_global_load_lds(
      (const __attribute__((address_space(1))) unsigned int*)g,
      (__attribute__((address_space(3))) unsigned int*)l, 16, 0, 0);
}

// ---------------- K0: all 4 weight transposes in ONE launch ----------------
__global__ void k_transp4(const float* __restrict__ cw, const float* __restrict__ aw,
                          const float* __restrict__ gw, const float* __restrict__ gu,
                          u16* __restrict__ cwT, u16* __restrict__ awT,
                          u16* __restrict__ gwT, u16* __restrict__ guT) {
  int b = blockIdx.x;
  const float* in; u16* out; int R, C, base;
  if (b < 128)       { in = cw; out = cwT; R = 128; C = 256; base = 0; }
  else if (b < 384)  { in = aw; out = awT; R = 256; C = 256; base = 128; }
  else if (b < 1152) { in = gw; out = gwT; R = 256; C = 768; base = 384; }
  else               { in = gu; out = guT; R = 256; C = 768; base = 1152; }
  int i = (b - base) * 256 + threadIdx.x;
  if (i < R * C) {
    int r = i / C, c = i % C;
    out[(size_t)c * R + r] = f2bf(in[i]);
  }
}

// ---------------- K1/K3: bf16 MFMA GEMM, 128x256 tile, BK=32, 512 thr ----------------
// 2-phase double-buffered; ONE barrier per K-step.
// AMODE 0: A fp32 row-major [M][K] (K1: x), load->convert->ds_write staging.
// AMODE 1: A bf16 chunked x_att [seg][k>>6][t][64], rows m = seg*TC + tt (TC=32),
//          staged via global_load_lds.
// STORE_T: write chunked convT layout [seg][f>>6][f&63][t]. Else row-major [M][Nld].
template <bool RELU, bool STORE_T, int AMODE>
__global__ __launch_bounds__(512, 2) void k_gemm(
    const void* __restrict__ Av, const u16* __restrict__ Bt,
    const float* __restrict__ bias, u16* __restrict__ out, int K, int Nld, int t0) {
  __shared__ __attribute__((aligned(16))) u16 ldsA[2][4096];   // [c 4][row 128][8]
  __shared__ __attribute__((aligned(16))) u16 ldsB[2][8192];   // [c 4][row 256][8]
  const int tid  = threadIdx.x;
  const int w    = tid >> 6;
  const int lane = tid & 63;
  const int quad = lane >> 4;
  const int l16  = lane & 15;
  const int m0 = blockIdx.x * 128;
  const int n0 = blockIdx.y * 256;
  const int wm = w >> 2, wn = w & 3;          // 2x4 wave grid, wave tile 64x64
  const int arow = tid & 127, ac = tid >> 7;  // A staging: (row, k-subchunk)
  const float* Af = (const float*)Av;
  const u16*   Ax = (const u16*)Av;

  f32x4 acc[4][4];
#pragma unroll
  for (int i = 0; i < 4; i++)
#pragma unroll
    for (int j = 0; j < 4; j++) acc[i][j] = f32x4{0.f, 0.f, 0.f, 0.f};

  // ---- prologue: stage k0=0 into buffer 0 ----
  float4 p0, p1;
  if (AMODE == 0) {
    const float* p = Af + (size_t)(m0 + arow) * K + ac * 8;
    p0 = *(const float4*)p;
    p1 = *(const float4*)(p + 4);
  } else {
    int r = m0 + arow, kk = ac * 8;
    gl16(Ax + (size_t)(r >> 5) * 65536 + (size_t)(kk >> 6) * 16384 +
             (t0 + (r & 31)) * 64 + (kk & 63),
         &ldsA[0][tid * 8]);
  }
#pragma unroll
  for (int i = 0; i < 2; i++) {
    int idx = i * 512 + tid, brow = idx & 255, bc = idx >> 8;
    gl16(Bt + (size_t)(n0 + brow) * K + bc * 8, &ldsB[0][idx * 8]);
  }
  if (AMODE == 0) {
    *(ushort4*)&ldsA[0][tid * 8]     = ushort4{f2bf(p0.x), f2bf(p0.y), f2bf(p0.z), f2bf(p0.w)};
    *(ushort4*)&ldsA[0][tid * 8 + 4] = ushort4{f2bf(p1.x), f2bf(p1.y), f2bf(p1.z), f2bf(p1.w)};
  }
  __syncthreads();

  int cur = 0;
  for (int k0 = 0; k0 < K; k0 += 32) {
    const int kn = k0 + 32;
    const bool more = kn < K;
    float4 q0, q1;
    if (more) {
      if (AMODE == 0) {
        const float* p = Af + (size_t)(m0 + arow) * K + kn + ac * 8;
        q0 = *(const float4*)p;
        q1 = *(const float4*)(p + 4);
      } else {
        int r = m0 + arow, kk = kn + ac * 8;
        gl16(Ax + (size_t)(r >> 5) * 65536 + (size_t)(kk >> 6) * 16384 +
                 (t0 + (r & 31)) * 64 + (kk & 63),
             &ldsA[cur ^ 1][tid * 8]);
      }
#pragma unroll
      for (int i = 0; i < 2; i++) {
        int idx = i * 512 + tid, brow = idx & 255, bc = idx >> 8;
        gl16(Bt + (size_t)(n0 + brow) * K + kn + bc * 8, &ldsB[cur ^ 1][idx * 8]);
      }
    }
    bf16x8 a[4], b[4];
#pragma unroll
    for (int i = 0; i < 4; i++)
      a[i] = *(const bf16x8*)&ldsA[cur][(quad * 128 + wm * 64 + i * 16 + l16) * 8];
#pragma unroll
    for (int j = 0; j < 4; j++)
      b[j] = *(const bf16x8*)&ldsB[cur][(quad * 256 + wn * 64 + j * 16 + l16) * 8];
#pragma unroll
    for (int i = 0; i < 4; i++)
#pragma unroll
      for (int j = 0; j < 4; j++)
        acc[i][j] = __builtin_amdgcn_mfma_f32_16x16x32_bf16(a[i], b[j], acc[i][j], 0, 0, 0);
    if (AMODE == 0 && more) {
      *(ushort4*)&ldsA[cur ^ 1][tid * 8]     = ushort4{f2bf(q0.x), f2bf(q0.y), f2bf(q0.z), f2bf(q0.w)};
      *(ushort4*)&ldsA[cur ^ 1][tid * 8 + 4] = ushort4{f2bf(q1.x), f2bf(q1.y), f2bf(q1.z), f2bf(q1.w)};
    }
    __syncthreads();
    cur ^= 1;
  }

#pragma unroll
  for (int j = 0; j < 4; j++) {
    int col = n0 + wn * 64 + j * 16 + l16;
    float bv = bias[col];
#pragma unroll
    for (int i = 0; i < 4; i++) {
      int row0 = m0 + wm * 64 + i * 16 + quad * 4;  // 4 consecutive rows
      if (STORE_T) {
        int nseg = row0 >> 8, tt0 = row0 & 255;
        ushort4 o;
        float v0 = acc[i][j][0] + bv, v1 = acc[i][j][1] + bv;
        float v2 = acc[i][j][2] + bv, v3 = acc[i][j][3] + bv;
        if (RELU) {
          v0 = fmaxf(v0, 0.f); v1 = fmaxf(v1, 0.f);
          v2 = fmaxf(v2, 0.f); v3 = fmaxf(v3, 0.f);
        }
        o.x = f2bf(v0); o.y = f2bf(v1); o.z = f2bf(v2); o.w = f2bf(v3);
        *(ushort4*)&out[(size_t)nseg * 65536 + (size_t)(col >> 6) * 16384 +
                        (col & 63) * 256 + tt0] = o;
      } else {
#pragma unroll
        for (int r = 0; r < 4; r++) {
          float v = acc[i][j][r] + bv;
          if (RELU) v = fmaxf(v, 0.f);
          out[(size_t)(row0 + r) * Nld + col] = f2bf(v);
        }
      }
    }
  }
}

// ---------------- K2: attention (in-place on xac) ----------------
// W read directly from global (L2-resident). Epilogue: per-wave LDS transpose
// for 16B coalesced stores; xbuf padded to 76 u16 (152B) to break the ~4-way
// write-bank aliasing the 72-pad version showed (SQ_LDS_BANK_CONFLICT 524K).
__global__ __launch_bounds__(256, 3) void k_attn(
    u16* xac,
    const u16* __restrict__ Wt,       // attn_w^T: [t'][t] 256x256
    const float* __restrict__ attn_b) {
  __shared__ u16 ldsC[16384];         // conv resident [tchunk 32][f 64][8]
  __shared__ float redmax[4][64];
  __shared__ float redsum[4][64];
  __shared__ __attribute__((aligned(16))) u16 xbuf[4][16][76];  // per-wave transpose
  const int tid  = threadIdx.x;
  const int w    = tid >> 6;
  const int lane = tid & 63;
  const int quad = lane >> 4;
  const int l16  = lane & 15;
  const int seg = blockIdx.x;
  const int c4  = blockIdx.y;
  u16* reg = xac + (size_t)seg * 65536 + (size_t)c4 * 16384;

  {
    const int f = tid & 63, g = tid >> 6;
#pragma unroll
    for (int u = 0; u < 8; u++) {
      int tch = g * 8 + u;
      *(bf16x8*)&ldsC[(tch * 64 + f) * 8] =
          *(const bf16x8*)(reg + (size_t)f * 256 + tch * 8);
    }
  }
  __syncthreads();

  f32x4 acc[4][4];
#pragma unroll
  for (int i = 0; i < 4; i++)
#pragma unroll
    for (int j = 0; j < 4; j++) acc[i][j] = f32x4{0.f, 0.f, 0.f, 0.f};

#pragma unroll
  for (int s = 0; s < 8; s++) {
    int k0 = s * 32;
    bf16x8 a[4], b[4];
#pragma unroll
    for (int i = 0; i < 4; i++)
      a[i] = *(const bf16x8*)(Wt + (size_t)(w * 64 + i * 16 + l16) * 256 + k0 + quad * 8);
#pragma unroll
    for (int j = 0; j < 4; j++)
      b[j] = *(const bf16x8*)&ldsC[((s * 4 + quad) * 64 + j * 16 + l16) * 8];
#pragma unroll
    for (int i = 0; i < 4; i++)
#pragma unroll
      for (int j = 0; j < 4; j++)
        acc[i][j] = __builtin_amdgcn_mfma_f32_16x16x32_bf16(a[i], b[j], acc[i][j], 0, 0, 0);
  }

#pragma unroll
  for (int i = 0; i < 4; i++)
#pragma unroll
    for (int r = 0; r < 4; r++) {
      float ab = attn_b[w * 64 + i * 16 + quad * 4 + r];
#pragma unroll
      for (int j = 0; j < 4; j++) acc[i][j][r] += ab;
    }

  float lmax[4];
#pragma unroll
  for (int j = 0; j < 4; j++) {
    float m = -1e30f;
#pragma unroll
    for (int i = 0; i < 4; i++)
#pragma unroll
      for (int r = 0; r < 4; r++) m = fmaxf(m, acc[i][j][r]);
    m = fmaxf(m, __shfl_xor(m, 16));
    m = fmaxf(m, __shfl_xor(m, 32));
    lmax[j] = m;
  }
  if (quad == 0) {
#pragma unroll
    for (int j = 0; j < 4; j++) redmax[w][j * 16 + l16] = lmax[j];
  }
  __syncthreads();
  float gmax[4];
#pragma unroll
  for (int j = 0; j < 4; j++) {
    int c = j * 16 + l16;
    gmax[j] = fmaxf(fmaxf(redmax[0][c], redmax[1][c]), fmaxf(redmax[2][c], redmax[3][c]));
  }
  float lsum[4];
#pragma unroll
  for (int j = 0; j < 4; j++) {
    float sacc = 0.f;
#pragma unroll
    for (int i = 0; i < 4; i++)
#pragma unroll
      for (int r = 0; r < 4; r++) {
        float e = __expf(acc[i][j][r] - gmax[j]);
        acc[i][j][r] = e;
        sacc += e;
      }
    sacc += __shfl_xor(sacc, 16);
    sacc += __shfl_xor(sacc, 32);
    lsum[j] = sacc;
  }
  if (quad == 0) {
#pragma unroll
    for (int j = 0; j < 4; j++) redsum[w][j * 16 + l16] = lsum[j];
  }
  __syncthreads();
  float rinv[4];
#pragma unroll
  for (int j = 0; j < 4; j++) {
    int c = j * 16 + l16;
    rinv[j] = 1.0f / (redsum[0][c] + redsum[1][c] + redsum[2][c] + redsum[3][c]);
  }

  // epilogue: per-wave LDS transpose -> 16B coalesced stores
#pragma unroll
  for (int i = 0; i < 4; i++) {
#pragma unroll
    for (int r = 0; r < 4; r++) {
      int tp = w * 64 + i * 16 + quad * 4 + r;
#pragma unroll
      for (int j = 0; j < 4; j++) {
        int fl = j * 16 + l16;
        float cv = bf2f(ldsC[((tp >> 3) * 64 + fl) * 8 + (tp & 7)]);
        float xa = acc[i][j][r] * rinv[j] * cv;
        xbuf[w][quad * 4 + r][fl] = f2bf(xa);   // within-wave buffer
      }
    }
    int rr = lane >> 2, oc = lane & 3;
    u16x8 v0 = *(const u16x8*)&xbuf[w][rr][oc * 16];
    u16x8 v1 = *(const u16x8*)&xbuf[w][rr][oc * 16 + 8];
    int tpb = w * 64 + i * 16 + rr;
    *(u16x8*)&reg[(size_t)tpb * 64 + oc * 16]     = v0;
    *(u16x8*)&reg[(size_t)tpb * 64 + oc * 16 + 8] = v1;
  }
}

// ---------------- K4: GRU scan, LDS-traffic-minimized ----------------
// Theory: old scan was LDS-pipe-bound (~4200 cyc/step/CU: 128 uls b128 reads +
// 64 8-way-conflicted ah reads + writes). Fix:
//  (a) ALL 6 Ut fragment sets register-resident (192 VGPR) — launch_bounds
//      (512,1) lifts the VGPR cap to 512 (est ~310 used, no spill; all static
//      indexing). Deletes 128 b128 LDS reads per CU per step.
//  (b) h stored in MFMA-fragment order hbT[s 8][quad 4][seg 16][e 8]:
//      the ah read for (s,quad) is 64 lanes covering one contiguous 1KB span
//      -> zero bank conflicts (was 8-way at stride 528B). Writes are 8 scalar
//      b16/thread at <=2-way aliasing (free per m136).
//  (c) double-buffered hbT (2 x 8KB) -> ONE barrier/step; LDS 145KB -> 16KB.
// Gate loads stay register-prefetched one step ahead (HBM latency hidden).
__global__ __launch_bounds__(512, 1) void k_scan(
    const u16* __restrict__ gc,   // gates chunk [NSEG*TC][768] (x@W + bi)
    const u16* __restrict__ Ut,   // gru_u^T [768][256]
    const float* __restrict__ br, // gru_b[1]: [768]
    float* __restrict__ hio,      // [NSEG][256] fp32 (d_out)
    int init) {
  __shared__ __attribute__((aligned(16))) u16 hbT[2][4096]; // [s][quad][seg][e]
  const int tid  = threadIdx.x;
  const int w    = tid >> 6;
  const int lane = tid & 63;
  const int quad = lane >> 4;
  const int l16  = lane & 15;
  const int n0 = blockIdx.x * 16;
  const int cg[2] = {w, 8 + w};   // two col-groups per wave (per gate)

  // ALL Ut fragments in VGPRs: [grp][gate][s], 48 x bf16x8 = 192 VGPR
  bf16x8 U[2][3][8];
#pragma unroll
  for (int grp = 0; grp < 2; grp++)
#pragma unroll
    for (int g = 0; g < 3; g++)
#pragma unroll
      for (int s = 0; s < 8; s++)
        U[grp][g][s] = *(const bf16x8*)(Ut + (size_t)(g * 256 + cg[grp] * 16 + l16) * 256 + s * 32 + quad * 8);

  float brZ[2], brR[2], brH[2];
#pragma unroll
  for (int grp = 0; grp < 2; grp++) {
    int c = cg[grp] * 16 + l16;
    brZ[grp] = br[c]; brR[grp] = br[256 + c]; brH[grp] = br[512 + c];
  }

  // h init: registers + hbT[0] (each thread writes exactly its 8 (grp,r) slots;
  // 512 thr x 8 = 4096 = full 16 seg x 256 col coverage)
  float hreg[2][4];
#pragma unroll
  for (int grp = 0; grp < 2; grp++)
#pragma unroll
    for (int r = 0; r < 4; r++) {
      hreg[grp][r] = init ? 0.f
                          : hio[(size_t)(n0 + quad * 4 + r) * 256 + cg[grp] * 16 + l16];
      int c = cg[grp] * 16 + l16;
      int seg = quad * 4 + r;
      hbT[0][(c >> 5) * 512 + ((c >> 3) & 3) * 128 + seg * 8 + (c & 7)] = f2bf(hreg[grp][r]);
    }

  // gates row bases for this lane's 4 segs
  const u16* gseg[4];
#pragma unroll
  for (int r = 0; r < 4; r++)
    gseg[r] = gc + (size_t)(n0 + quad * 4 + r) * TC * 768;
  __syncthreads();

  // gate prefetch buffers (raw u16; bf2f at use)
  u16 gA[2][3][4], gB[2][3][4];
  auto load_g = [&](int tt, u16 (&gr)[2][3][4]) {
#pragma unroll
    for (int grp = 0; grp < 2; grp++)
#pragma unroll
      for (int g = 0; g < 3; g++)
#pragma unroll
        for (int r = 0; r < 4; r++)
          gr[grp][g][r] = gseg[r][tt * 768 + g * 256 + cg[grp] * 16 + l16];
  };

  auto step = [&](int tt, const u16 (&gcur)[2][3][4], u16 (&gnext)[2][3][4],
                  const u16* hR, u16* hW) {
    if (tt + 1 < TC) load_g(tt + 1, gnext);

    f32x4 acc[2][3];
#pragma unroll
    for (int grp = 0; grp < 2; grp++)
#pragma unroll
      for (int g = 0; g < 3; g++) acc[grp][g] = f32x4{0.f, 0.f, 0.f, 0.f};

#pragma unroll
    for (int s = 0; s < 8; s++) {
      // conflict-free: 64 lanes read one contiguous 1KB span
      bf16x8 ah = *(const bf16x8*)&hR[s * 512 + quad * 128 + l16 * 8];
#pragma unroll
      for (int grp = 0; grp < 2; grp++)
#pragma unroll
        for (int g = 0; g < 3; g++)
          acc[grp][g] = __builtin_amdgcn_mfma_f32_16x16x32_bf16(ah, U[grp][g][s], acc[grp][g], 0, 0, 0);
    }

#pragma unroll
    for (int grp = 0; grp < 2; grp++)
#pragma unroll
      for (int r = 0; r < 4; r++) {
        float z  = sigm(acc[grp][0][r] + bf2f(gcur[grp][0][r]) + brZ[grp]);
        float rg = sigm(acc[grp][1][r] + bf2f(gcur[grp][1][r]) + brR[grp]);
        float hh = fmaxf(bf2f(gcur[grp][2][r]) + rg * (acc[grp][2][r] + brH[grp]), 0.f);
        float hn = z * hreg[grp][r] + (1.0f - z) * hh;
        hreg[grp][r] = hn;
        int c = cg[grp] * 16 + l16;
        int seg = quad * 4 + r;
        hW[(c >> 5) * 512 + ((c >> 3) & 3) * 128 + seg * 8 + (c & 7)] = f2bf(hn);
      }
    __syncthreads();   // hW visible; all hR reads retired
  };

  load_g(0, gA);
  for (int t2 = 0; t2 < TC; t2 += 2) {
    step(t2,     gA, gB, hbT[0], hbT[1]);
    step(t2 + 1, gB, gA, hbT[1], hbT[0]);
  }

#pragma unroll
  for (int grp = 0; grp < 2; grp++)
#pragma unroll
    for (int r = 0; r < 4; r++)
      hio[(size_t)(n0 + quad * 4 + r) * 256 + cg[grp] * 16 + l16] = hreg[grp][r];
}

// ---------------- host ----------------
extern "C" void kernel_launch(void* const* d_in, const int* in_sizes, int n_in,
                              void* d_out, int out_size, void* d_ws, size_t ws_size,
                              hipStream_t stream) {
  (void)in_sizes; (void)n_in; (void)out_size;
  const float* x      = (const float*)d_in[0];
  const float* conv_w = (const float*)d_in[1];
  const float* conv_b = (const float*)d_in[2];
  const float* attn_w = (const float*)d_in[3];
  const float* attn_b = (const float*)d_in[4];
  const float* gru_w  = (const float*)d_in[5];
  const float* gru_u  = (const float*)d_in[6];
  const float* gru_b  = (const float*)d_in[7];

  // scratch layout: 185,532,416 B total (known-safe: < 202,309,696 proven)
  const size_t NEEDED = 185532416;
  if (ws_size < NEEDED) return;
  char* ws = (char*)d_ws;
  u16* xac     = (u16*)(ws);                  // 134217728 B: convT then x_att (chunked, in-place)
  u16* gatesC  = (u16*)(ws + 134217728);      //  50331648 B: gates for one 32-step chunk
  u16* conv_wT = (u16*)(ws + 184549376);      //     65536 B [f][c]
  u16* attn_wT = (u16*)(ws + 184614912);      //    131072 B [t'][t]
  u16* gru_wT  = (u16*)(ws + 184745984);      //    393216 B [j][f]
  u16* gru_uT  = (u16*)(ws + 185139200);      //    393216 B [j][k]

  hipLaunchKernelGGL(k_transp4, dim3(1920), dim3(256), 0, stream,
                     conv_w, attn_w, gru_w, gru_u, conv_wT, attn_wT, gru_wT, gru_uT);

  // K1: conv = relu(x @ conv_w + b); full N=256 per block -> fp32 A read ONCE
  hipLaunchKernelGGL((k_gemm<true, true, 0>), dim3(2048, 1), dim3(512), 0, stream,
                     (const void*)x, conv_wT, conv_b, xac, 128, 0, 0);
  // K2: attention softmax + multiply, in place on xac
  hipLaunchKernelGGL(k_attn, dim3(1024, 4), dim3(256), 0, stream,
                     xac, attn_wT, attn_b);
  // K3/K4: 8 time chunks of (gates GEMM -> 32-step scan); h lives in d_out
  for (int c = 0; c < 8; c++) {
    hipLaunchKernelGGL((k_gemm<false, false, 1>), dim3(256, 3), dim3(512), 0, stream,
                       (const void*)xac, gru_wT, gru_b, gatesC, 256, 768, c * TC);
    hipLaunchKernelGGL(k_scan, dim3(64), dim3(512), 0, stream,
                       gatesC, gru_uT, gru_b + 768, (float*)d_out, c == 0 ? 1 : 0);
  }
}

// Round 6
// 1222.761 us; speedup vs baseline: 1.3400x; 1.3400x over previous
//
#include <hip/hip_runtime.h>
#include <stdint.h>

typedef unsigned short u16;
typedef __attribute__((ext_vector_type(8))) __bf16 bf16x8;
typedef __attribute__((ext_vector_type(8))) u16 u16x8;
typedef __attribute__((ext_vector_type(4))) float f32x4;

#define TTS 256
#define NSEG 1024
#define TC 32            // time-chunk for gates

__device__ __forceinline__ u16 f2bf(float f) {
  union { float f; uint32_t u; } v; v.f = f;
  uint32_t r = v.u + 0x7fffu + ((v.u >> 16) & 1u);
  return (u16)(r >> 16);
}
__device__ __forceinline__ float bf2f(u16 h) {
  union { uint32_t u; float f; } v; v.u = ((uint32_t)h) << 16;
  return v.f;
}
__device__ __forceinline__ float sigm(float x) {
  return __builtin_amdgcn_rcpf(1.0f + __expf(-x));
}
// async global->LDS, 16B per lane; LDS dest must be wave-uniform base + lane*16
__device__ __forceinline__ void gl16(const void* g, void* l) {
  __builtin_amdgcn_global_load_lds(
      (const __attribute__((address_space(1))) unsigned int*)g,
      (__attribute__((address_space(3))) unsigned int*)l, 16, 0, 0);
}

// ---------------- K0: all 4 weight transposes in ONE launch ----------------
__global__ void k_transp4(const float* __restrict__ cw, const float* __restrict__ aw,
                          const float* __restrict__ gw, const float* __restrict__ gu,
                          u16* __restrict__ cwT, u16* __restrict__ awT,
                          u16* __restrict__ gwT, u16* __restrict__ guT) {
  int b = blockIdx.x;
  const float* in; u16* out; int R, C, base;
  if (b < 128)       { in = cw; out = cwT; R = 128; C = 256; base = 0; }
  else if (b < 384)  { in = aw; out = awT; R = 256; C = 256; base = 128; }
  else if (b < 1152) { in = gw; out = gwT; R = 256; C = 768; base = 384; }
  else               { in = gu; out = guT; R = 256; C = 768; base = 1152; }
  int i = (b - base) * 256 + threadIdx.x;
  if (i < R * C) {
    int r = i / C, c = i % C;
    out[(size_t)c * R + r] = f2bf(in[i]);
  }
}

// ---------------- K1/K3: bf16 MFMA GEMM, 128x256 tile, BK=32, 512 thr ----------------
// 2-phase double-buffered; ONE barrier per K-step.
// AMODE 0: A fp32 row-major [M][K] (K1: x), load->convert->ds_write staging.
// AMODE 1: A bf16 chunked x_att [seg][k>>6][t][64], staged via global_load_lds.
// STORE_T: write chunked convT layout [seg][f>>6][f&63][t]. Else row-major [M][Nld].
template <bool RELU, bool STORE_T, int AMODE>
__global__ __launch_bounds__(512, 2) void k_gemm(
    const void* __restrict__ Av, const u16* __restrict__ Bt,
    const float* __restrict__ bias, u16* __restrict__ out, int K, int Nld, int t0) {
  __shared__ __attribute__((aligned(16))) u16 ldsA[2][4096];   // [c 4][row 128][8]
  __shared__ __attribute__((aligned(16))) u16 ldsB[2][8192];   // [c 4][row 256][8]
  const int tid  = threadIdx.x;
  const int w    = tid >> 6;
  const int lane = tid & 63;
  const int quad = lane >> 4;
  const int l16  = lane & 15;
  const int m0 = blockIdx.x * 128;
  const int n0 = blockIdx.y * 256;
  const int wm = w >> 2, wn = w & 3;          // 2x4 wave grid, wave tile 64x64
  const int arow = tid & 127, ac = tid >> 7;  // A staging: (row, k-subchunk)
  const float* Af = (const float*)Av;
  const u16*   Ax = (const u16*)Av;

  f32x4 acc[4][4];
#pragma unroll
  for (int i = 0; i < 4; i++)
#pragma unroll
    for (int j = 0; j < 4; j++) acc[i][j] = f32x4{0.f, 0.f, 0.f, 0.f};

  // ---- prologue: stage k0=0 into buffer 0 ----
  float4 p0, p1;
  if (AMODE == 0) {
    const float* p = Af + (size_t)(m0 + arow) * K + ac * 8;
    p0 = *(const float4*)p;
    p1 = *(const float4*)(p + 4);
  } else {
    int r = m0 + arow, kk = ac * 8;
    gl16(Ax + (size_t)(r >> 5) * 65536 + (size_t)(kk >> 6) * 16384 +
             (t0 + (r & 31)) * 64 + (kk & 63),
         &ldsA[0][tid * 8]);
  }
#pragma unroll
  for (int i = 0; i < 2; i++) {
    int idx = i * 512 + tid, brow = idx & 255, bc = idx >> 8;
    gl16(Bt + (size_t)(n0 + brow) * K + bc * 8, &ldsB[0][idx * 8]);
  }
  if (AMODE == 0) {
    *(ushort4*)&ldsA[0][tid * 8]     = ushort4{f2bf(p0.x), f2bf(p0.y), f2bf(p0.z), f2bf(p0.w)};
    *(ushort4*)&ldsA[0][tid * 8 + 4] = ushort4{f2bf(p1.x), f2bf(p1.y), f2bf(p1.z), f2bf(p1.w)};
  }
  __syncthreads();

  int cur = 0;
  for (int k0 = 0; k0 < K; k0 += 32) {
    const int kn = k0 + 32;
    const bool more = kn < K;
    float4 q0, q1;
    if (more) {
      if (AMODE == 0) {
        const float* p = Af + (size_t)(m0 + arow) * K + kn + ac * 8;
        q0 = *(const float4*)p;
        q1 = *(const float4*)(p + 4);
      } else {
        int r = m0 + arow, kk = kn + ac * 8;
        gl16(Ax + (size_t)(r >> 5) * 65536 + (size_t)(kk >> 6) * 16384 +
                 (t0 + (r & 31)) * 64 + (kk & 63),
             &ldsA[cur ^ 1][tid * 8]);
      }
#pragma unroll
      for (int i = 0; i < 2; i++) {
        int idx = i * 512 + tid, brow = idx & 255, bc = idx >> 8;
        gl16(Bt + (size_t)(n0 + brow) * K + kn + bc * 8, &ldsB[cur ^ 1][idx * 8]);
      }
    }
    bf16x8 a[4], b[4];
#pragma unroll
    for (int i = 0; i < 4; i++)
      a[i] = *(const bf16x8*)&ldsA[cur][(quad * 128 + wm * 64 + i * 16 + l16) * 8];
#pragma unroll
    for (int j = 0; j < 4; j++)
      b[j] = *(const bf16x8*)&ldsB[cur][(quad * 256 + wn * 64 + j * 16 + l16) * 8];
#pragma unroll
    for (int i = 0; i < 4; i++)
#pragma unroll
      for (int j = 0; j < 4; j++)
        acc[i][j] = __builtin_amdgcn_mfma_f32_16x16x32_bf16(a[i], b[j], acc[i][j], 0, 0, 0);
    if (AMODE == 0 && more) {
      *(ushort4*)&ldsA[cur ^ 1][tid * 8]     = ushort4{f2bf(q0.x), f2bf(q0.y), f2bf(q0.z), f2bf(q0.w)};
      *(ushort4*)&ldsA[cur ^ 1][tid * 8 + 4] = ushort4{f2bf(q1.x), f2bf(q1.y), f2bf(q1.z), f2bf(q1.w)};
    }
    __syncthreads();
    cur ^= 1;
  }

#pragma unroll
  for (int j = 0; j < 4; j++) {
    int col = n0 + wn * 64 + j * 16 + l16;
    float bv = bias[col];
#pragma unroll
    for (int i = 0; i < 4; i++) {
      int row0 = m0 + wm * 64 + i * 16 + quad * 4;  // 4 consecutive rows
      if (STORE_T) {
        int nseg = row0 >> 8, tt0 = row0 & 255;
        ushort4 o;
        float v0 = acc[i][j][0] + bv, v1 = acc[i][j][1] + bv;
        float v2 = acc[i][j][2] + bv, v3 = acc[i][j][3] + bv;
        if (RELU) {
          v0 = fmaxf(v0, 0.f); v1 = fmaxf(v1, 0.f);
          v2 = fmaxf(v2, 0.f); v3 = fmaxf(v3, 0.f);
        }
        o.x = f2bf(v0); o.y = f2bf(v1); o.z = f2bf(v2); o.w = f2bf(v3);
        *(ushort4*)&out[(size_t)nseg * 65536 + (size_t)(col >> 6) * 16384 +
                        (col & 63) * 256 + tt0] = o;
      } else {
#pragma unroll
        for (int r = 0; r < 4; r++) {
          float v = acc[i][j][r] + bv;
          if (RELU) v = fmaxf(v, 0.f);
          out[(size_t)(row0 + r) * Nld + col] = f2bf(v);
        }
      }
    }
  }
}

// ---------------- K2: attention (in-place on xac) ----------------
// W read directly from global (L2-resident). Epilogue: per-wave LDS transpose
// for 16B coalesced stores; xbuf padded to 76 u16.
__global__ __launch_bounds__(256, 3) void k_attn(
    u16* xac,
    const u16* __restrict__ Wt,       // attn_w^T: [t'][t] 256x256
    const float* __restrict__ attn_b) {
  __shared__ u16 ldsC[16384];         // conv resident [tchunk 32][f 64][8]
  __shared__ float redmax[4][64];
  __shared__ float redsum[4][64];
  __shared__ __attribute__((aligned(16))) u16 xbuf[4][16][76];  // per-wave transpose
  const int tid  = threadIdx.x;
  const int w    = tid >> 6;
  const int lane = tid & 63;
  const int quad = lane >> 4;
  const int l16  = lane & 15;
  const int seg = blockIdx.x;
  const int c4  = blockIdx.y;
  u16* reg = xac + (size_t)seg * 65536 + (size_t)c4 * 16384;

  {
    const int f = tid & 63, g = tid >> 6;
#pragma unroll
    for (int u = 0; u < 8; u++) {
      int tch = g * 8 + u;
      *(bf16x8*)&ldsC[(tch * 64 + f) * 8] =
          *(const bf16x8*)(reg + (size_t)f * 256 + tch * 8);
    }
  }
  __syncthreads();

  f32x4 acc[4][4];
#pragma unroll
  for (int i = 0; i < 4; i++)
#pragma unroll
    for (int j = 0; j < 4; j++) acc[i][j] = f32x4{0.f, 0.f, 0.f, 0.f};

#pragma unroll
  for (int s = 0; s < 8; s++) {
    int k0 = s * 32;
    bf16x8 a[4], b[4];
#pragma unroll
    for (int i = 0; i < 4; i++)
      a[i] = *(const bf16x8*)(Wt + (size_t)(w * 64 + i * 16 + l16) * 256 + k0 + quad * 8);
#pragma unroll
    for (int j = 0; j < 4; j++)
      b[j] = *(const bf16x8*)&ldsC[((s * 4 + quad) * 64 + j * 16 + l16) * 8];
#pragma unroll
    for (int i = 0; i < 4; i++)
#pragma unroll
      for (int j = 0; j < 4; j++)
        acc[i][j] = __builtin_amdgcn_mfma_f32_16x16x32_bf16(a[i], b[j], acc[i][j], 0, 0, 0);
  }

#pragma unroll
  for (int i = 0; i < 4; i++)
#pragma unroll
    for (int r = 0; r < 4; r++) {
      float ab = attn_b[w * 64 + i * 16 + quad * 4 + r];
#pragma unroll
      for (int j = 0; j < 4; j++) acc[i][j][r] += ab;
    }

  float lmax[4];
#pragma unroll
  for (int j = 0; j < 4; j++) {
    float m = -1e30f;
#pragma unroll
    for (int i = 0; i < 4; i++)
#pragma unroll
      for (int r = 0; r < 4; r++) m = fmaxf(m, acc[i][j][r]);
    m = fmaxf(m, __shfl_xor(m, 16));
    m = fmaxf(m, __shfl_xor(m, 32));
    lmax[j] = m;
  }
  if (quad == 0) {
#pragma unroll
    for (int j = 0; j < 4; j++) redmax[w][j * 16 + l16] = lmax[j];
  }
  __syncthreads();
  float gmax[4];
#pragma unroll
  for (int j = 0; j < 4; j++) {
    int c = j * 16 + l16;
    gmax[j] = fmaxf(fmaxf(redmax[0][c], redmax[1][c]), fmaxf(redmax[2][c], redmax[3][c]));
  }
  float lsum[4];
#pragma unroll
  for (int j = 0; j < 4; j++) {
    float sacc = 0.f;
#pragma unroll
    for (int i = 0; i < 4; i++)
#pragma unroll
      for (int r = 0; r < 4; r++) {
        float e = __expf(acc[i][j][r] - gmax[j]);
        acc[i][j][r] = e;
        sacc += e;
      }
    sacc += __shfl_xor(sacc, 16);
    sacc += __shfl_xor(sacc, 32);
    lsum[j] = sacc;
  }
  if (quad == 0) {
#pragma unroll
    for (int j = 0; j < 4; j++) redsum[w][j * 16 + l16] = lsum[j];
  }
  __syncthreads();
  float rinv[4];
#pragma unroll
  for (int j = 0; j < 4; j++) {
    int c = j * 16 + l16;
    rinv[j] = 1.0f / (redsum[0][c] + redsum[1][c] + redsum[2][c] + redsum[3][c]);
  }

  // epilogue: per-wave LDS transpose -> 16B coalesced stores
#pragma unroll
  for (int i = 0; i < 4; i++) {
#pragma unroll
    for (int r = 0; r < 4; r++) {
      int tp = w * 64 + i * 16 + quad * 4 + r;
#pragma unroll
      for (int j = 0; j < 4; j++) {
        int fl = j * 16 + l16;
        float cv = bf2f(ldsC[((tp >> 3) * 64 + fl) * 8 + (tp & 7)]);
        float xa = acc[i][j][r] * rinv[j] * cv;
        xbuf[w][quad * 4 + r][fl] = f2bf(xa);   // within-wave buffer
      }
    }
    int rr = lane >> 2, oc = lane & 3;
    u16x8 v0 = *(const u16x8*)&xbuf[w][rr][oc * 16];
    u16x8 v1 = *(const u16x8*)&xbuf[w][rr][oc * 16 + 8];
    int tpb = w * 64 + i * 16 + rr;
    *(u16x8*)&reg[(size_t)tpb * 64 + oc * 16]     = v0;
    *(u16x8*)&reg[(size_t)tpb * 64 + oc * 16 + 8] = v1;
  }
}

// ---------------- K4: GRU scan, register-resident U ----------------
// Round-5 showed VGPR_Count=128: the compiler re-fetched U (384KB/block) from
// cache EVERY step (remat/spill) -> 128us/dispatch, all pipes <6%. Fix:
//  (a) waves_per_eu(2,2): allocator budget = exactly 256 VGPR (8-wave block).
//  (b) U pinned with asm "+v" after load -> cannot be rematerialized.
//  (c) gates via global_load_lds into double-buffered LDS (frees ~48 VGPR),
//      PERMUTED so activation ds_reads are conflict-free: layout
//      [g 3][cg 16][r 4][quad 4][l16 16] (quad stride 32B, l16 stride 2B ->
//      32 banks x 2 lanes). gl16 dest is linear-in-tid (m104); the per-lane
//      GLOBAL source carries the permutation.
// h double-buffered in MFMA-fragment order (round-5 layout, verified) ->
// one barrier/step; barrier's vmcnt drain completes the gate staging.
__global__ __launch_bounds__(512) __attribute__((amdgpu_waves_per_eu(2, 2)))
void k_scan(
    const u16* __restrict__ gc,   // gates chunk [NSEG*TC][768] (x@W + bi)
    const u16* __restrict__ Ut,   // gru_u^T [768][256]
    const float* __restrict__ br, // gru_b[1]: [768]
    float* __restrict__ hio,      // [NSEG][256] fp32 (d_out)
    int init) {
  __shared__ __attribute__((aligned(16))) u16 hbT[2][4096];   // [s][quad][seg][e]
  __shared__ __attribute__((aligned(16))) u16 ldsG[2][12288]; // [g][cg][r][quad][l16]
  const int tid  = threadIdx.x;
  const int w    = tid >> 6;
  const int lane = tid & 63;
  const int quad = lane >> 4;
  const int l16  = lane & 15;
  const int n0 = blockIdx.x * 16;
  const int cg[2] = {w, 8 + w};   // two col-groups per wave (per gate)

  // ALL Ut fragments register-resident: [grp][gate][s], 48 x bf16x8 = 192 VGPR
  bf16x8 U[2][3][8];
#pragma unroll
  for (int grp = 0; grp < 2; grp++)
#pragma unroll
    for (int g = 0; g < 3; g++)
#pragma unroll
      for (int s = 0; s < 8; s++) {
        U[grp][g][s] = *(const bf16x8*)(Ut + (size_t)(g * 256 + cg[grp] * 16 + l16) * 256 + s * 32 + quad * 8);
        asm volatile("" : "+v"(U[grp][g][s]));   // pin: no remat, must stay live
      }

  float brZ[2], brR[2], brH[2];
#pragma unroll
  for (int grp = 0; grp < 2; grp++) {
    int c = cg[grp] * 16 + l16;
    brZ[grp] = br[c]; brR[grp] = br[256 + c]; brH[grp] = br[512 + c];
  }

  // uniform-per-thread index bases
  int gbase[2], hwb[2];
#pragma unroll
  for (int grp = 0; grp < 2; grp++) {
    gbase[grp] = cg[grp] * 256 + quad * 16 + l16;           // + g*4096 + r*64
    int c = cg[grp] * 16 + l16;
    hwb[grp] = (c >> 5) * 512 + ((c >> 3) & 3) * 128 + (c & 7) + quad * 32;  // + r*8
  }
  const int ahb = quad * 128 + l16 * 8;                     // + s*512

  // h init: registers + hbT[0]
  float hreg[2][4];
#pragma unroll
  for (int grp = 0; grp < 2; grp++)
#pragma unroll
    for (int r = 0; r < 4; r++) {
      hreg[grp][r] = init ? 0.f
                          : hio[(size_t)(n0 + quad * 4 + r) * 256 + cg[grp] * 16 + l16];
      hbT[0][hwb[grp] + r * 8] = f2bf(hreg[grp][r]);
    }

  // gate staging: this thread's 3 chunks (id = tid + k*512), permuted source
  const u16* sp[3];
#pragma unroll
  for (int k = 0; k < 3; k++) {
    int id = tid + k * 512;
    int a = id & 1, q = (id >> 1) & 3, r = (id >> 3) & 3;
    int cgv = (id >> 5) & 15, g = id >> 9;
    sp[k] = gc + ((size_t)(n0 + q * 4 + r) * 32 + 0) * 768 + g * 256 + cgv * 16 + a * 8;
  }
  // prologue: stage tt=0 into ldsG[0]
#pragma unroll
  for (int k = 0; k < 3; k++) {
    gl16(sp[k], &ldsG[0][(tid + k * 512) * 8]);
    sp[k] += 768;   // now points at tt=1
  }
  __syncthreads();   // hbT[0] visible; vmcnt drained -> ldsG[0] ready

  for (int tt = 0; tt < TC; tt++) {
    // stage next step's gates (consumed after next barrier)
    if (tt + 1 < TC) {
#pragma unroll
      for (int k = 0; k < 3; k++) {
        gl16(sp[k], &ldsG[(tt + 1) & 1][(tid + k * 512) * 8]);
        sp[k] += 768;
      }
    }

    f32x4 acc[2][3];
#pragma unroll
    for (int grp = 0; grp < 2; grp++)
#pragma unroll
      for (int g = 0; g < 3; g++) acc[grp][g] = f32x4{0.f, 0.f, 0.f, 0.f};

    const u16* hR = hbT[tt & 1];
#pragma unroll
    for (int s = 0; s < 8; s++) {
      bf16x8 ah = *(const bf16x8*)&hR[ahb + s * 512];   // contiguous 1KB span: conflict-free
#pragma unroll
      for (int grp = 0; grp < 2; grp++)
#pragma unroll
        for (int g = 0; g < 3; g++)
          acc[grp][g] = __builtin_amdgcn_mfma_f32_16x16x32_bf16(ah, U[grp][g][s], acc[grp][g], 0, 0, 0);
    }

    const u16* G = ldsG[tt & 1];
    u16* hW = hbT[(tt + 1) & 1];
#pragma unroll
    for (int grp = 0; grp < 2; grp++)
#pragma unroll
      for (int r = 0; r < 4; r++) {
        float gz = bf2f(G[gbase[grp] + 0 * 4096 + r * 64]);
        float gr = bf2f(G[gbase[grp] + 1 * 4096 + r * 64]);
        float gh = bf2f(G[gbase[grp] + 2 * 4096 + r * 64]);
        float z  = sigm(acc[grp][0][r] + gz + brZ[grp]);
        float rg = sigm(acc[grp][1][r] + gr + brR[grp]);
        float hh = fmaxf(gh + rg * (acc[grp][2][r] + brH[grp]), 0.f);
        float hn = z * hreg[grp][r] + (1.0f - z) * hh;
        hreg[grp][r] = hn;
        hW[hwb[grp] + r * 8] = f2bf(hn);
      }
    __syncthreads();   // hW visible; hR reads retired; next gates landed (vmcnt)
  }

#pragma unroll
  for (int grp = 0; grp < 2; grp++)
#pragma unroll
    for (int r = 0; r < 4; r++)
      hio[(size_t)(n0 + quad * 4 + r) * 256 + cg[grp] * 16 + l16] = hreg[grp][r];
}

// ---------------- host ----------------
extern "C" void kernel_launch(void* const* d_in, const int* in_sizes, int n_in,
                              void* d_out, int out_size, void* d_ws, size_t ws_size,
                              hipStream_t stream) {
  (void)in_sizes; (void)n_in; (void)out_size;
  const float* x      = (const float*)d_in[0];
  const float* conv_w = (const float*)d_in[1];
  const float* conv_b = (const float*)d_in[2];
  const float* attn_w = (const float*)d_in[3];
  const float* attn_b = (const float*)d_in[4];
  const float* gru_w  = (const float*)d_in[5];
  const float* gru_u  = (const float*)d_in[6];
  const float* gru_b  = (const float*)d_in[7];

  // scratch layout: 185,532,416 B total (known-safe: < 202,309,696 proven)
  const size_t NEEDED = 185532416;
  if (ws_size < NEEDED) return;
  char* ws = (char*)d_ws;
  u16* xac     = (u16*)(ws);                  // 134217728 B: convT then x_att (chunked, in-place)
  u16* gatesC  = (u16*)(ws + 134217728);      //  50331648 B: gates for one 32-step chunk
  u16* conv_wT = (u16*)(ws + 184549376);      //     65536 B [f][c]
  u16* attn_wT = (u16*)(ws + 184614912);      //    131072 B [t'][t]
  u16* gru_wT  = (u16*)(ws + 184745984);      //    393216 B [j][f]
  u16* gru_uT  = (u16*)(ws + 185139200);      //    393216 B [j][k]

  hipLaunchKernelGGL(k_transp4, dim3(1920), dim3(256), 0, stream,
                     conv_w, attn_w, gru_w, gru_u, conv_wT, attn_wT, gru_wT, gru_uT);

  // K1: conv = relu(x @ conv_w + b); full N=256 per block -> fp32 A read ONCE
  hipLaunchKernelGGL((k_gemm<true, true, 0>), dim3(2048, 1), dim3(512), 0, stream,
                     (const void*)x, conv_wT, conv_b, xac, 128, 0, 0);
  // K2: attention softmax + multiply, in place on xac
  hipLaunchKernelGGL(k_attn, dim3(1024, 4), dim3(256), 0, stream,
                     xac, attn_wT, attn_b);
  // K3/K4: 8 time chunks of (gates GEMM -> 32-step scan); h lives in d_out
  for (int c = 0; c < 8; c++) {
    hipLaunchKernelGGL((k_gemm<false, false, 1>), dim3(256, 3), dim3(512), 0, stream,
                       (const void*)xac, gru_wT, gru_b, gatesC, 256, 768, c * TC);
    hipLaunchKernelGGL(k_scan, dim3(64), dim3(512), 0, stream,
                       gatesC, gru_uT, gru_b + 768, (float*)d_out, c == 0 ? 1 : 0);
  }
}

// Round 7
// 1121.519 us; speedup vs baseline: 1.4610x; 1.0903x over previous
//
#include <hip/hip_runtime.h>
#include <stdint.h>

typedef unsigned short u16;
typedef __attribute__((ext_vector_type(8))) __bf16 bf16x8;
typedef __attribute__((ext_vector_type(8))) u16 u16x8;
typedef __attribute__((ext_vector_type(4))) float f32x4;

#define TTS 256
#define NSEG 1024
#define TC 32            // time-chunk for gates

__device__ __forceinline__ u16 f2bf(float f) {
  union { float f; uint32_t u; } v; v.f = f;
  uint32_t r = v.u + 0x7fffu + ((v.u >> 16) & 1u);
  return (u16)(r >> 16);
}
__device__ __forceinline__ float bf2f(u16 h) {
  union { uint32_t u; float f; } v; v.u = ((uint32_t)h) << 16;
  return v.f;
}
__device__ __forceinline__ float sigm(float x) {
  return __builtin_amdgcn_rcpf(1.0f + __expf(-x));
}
// async global->LDS, 16B per lane; LDS dest must be wave-uniform base + lane*16
__device__ __forceinline__ void gl16(const void* g, void* l) {
  __builtin_amdgcn_global_load_lds(
      (const __attribute__((address_space(1))) unsigned int*)g,
      (__attribute__((address_space(3))) unsigned int*)l, 16, 0, 0);
}

// ---------------- K0: all 4 weight transposes in ONE launch ----------------
__global__ void k_transp4(const float* __restrict__ cw, const float* __restrict__ aw,
                          const float* __restrict__ gw, const float* __restrict__ gu,
                          u16* __restrict__ cwT, u16* __restrict__ awT,
                          u16* __restrict__ gwT, u16* __restrict__ guT) {
  int b = blockIdx.x;
  const float* in; u16* out; int R, C, base;
  if (b < 128)       { in = cw; out = cwT; R = 128; C = 256; base = 0; }
  else if (b < 384)  { in = aw; out = awT; R = 256; C = 256; base = 128; }
  else if (b < 1152) { in = gw; out = gwT; R = 256; C = 768; base = 384; }
  else               { in = gu; out = guT; R = 256; C = 768; base = 1152; }
  int i = (b - base) * 256 + threadIdx.x;
  if (i < R * C) {
    int r = i / C, c = i % C;
    out[(size_t)c * R + r] = f2bf(in[i]);
  }
}

// ---------------- K1/K3: bf16 MFMA GEMM, 128x256 tile, BK=32, 512 thr ----------------
// COALESCED staging (round-7 fix): thread -> (row = tid>>2, kchunk = tid&3) so
// 4 consecutive lanes cover 64B contiguous per row (was lane=row at 512B stride:
// 2-4x over-fetch). LDS layout [row][slot 4][8] with slot = kchunk ^ (row&3)
// (XOR swizzle; gl16 dest stays linear-in-tid, SOURCE carries the permutation —
// both-sides-or-neither rule). MFMA reads use xsw = (quad^(l16&3))*8: bijective
// per 16-row x 64B tile -> optimal bank tiling.
// AMODE 0: A fp32 row-major (K1: x), load->convert->ds_write to swizzled slot.
// AMODE 1: A bf16 chunked x_att [seg][k>>6][t][64], gl16 with swizzled source.
// STORE_T: chunked conv layout [seg][f>>6][f&63][t] via per-wave LDS transpose
//          -> 128B-contiguous store runs (was 8B at 512B stride: 4x write amp).
template <bool RELU, bool STORE_T, int AMODE>
__global__ __launch_bounds__(512, 2) void k_gemm(
    const void* __restrict__ Av, const u16* __restrict__ Bt,
    const float* __restrict__ bias, u16* __restrict__ out, int K, int Nld, int t0) {
  __shared__ __attribute__((aligned(16))) u16 ldsA[2][4096];   // [row 128][slot 4][8]
  __shared__ __attribute__((aligned(16))) u16 ldsB[2][8192];   // [row 256][slot 4][8]
  __shared__ __attribute__((aligned(16))) u16 xw[STORE_T ? 8 * 16 * 70 : 16];
  const int tid  = threadIdx.x;
  const int w    = tid >> 6;
  const int lane = tid & 63;
  const int quad = lane >> 4;
  const int l16  = lane & 15;
  const int m0 = blockIdx.x * 128;
  const int n0 = blockIdx.y * 256;
  const int wm = w >> 2, wn = w & 3;          // 2x4 wave grid, wave tile 64x64
  const int srow = tid >> 2;                  // A staging row (0..127)
  const int scs  = (tid & 3) ^ (srow & 3);    // swizzled k-subchunk
  const int aslot = (srow * 4 + scs) * 8;     // ds_write dest (AMODE 0)
  const int xsw  = (quad ^ (l16 & 3)) * 8;    // MFMA-read slot swizzle
  const float* Af = (const float*)Av;
  const u16*   Ax = (const u16*)Av;

  f32x4 acc[4][4];
#pragma unroll
  for (int i = 0; i < 4; i++)
#pragma unroll
    for (int j = 0; j < 4; j++) acc[i][j] = f32x4{0.f, 0.f, 0.f, 0.f};

  // ---- prologue: stage k0=0 into buffer 0 ----
  float4 p0, p1;
  if (AMODE == 0) {
    const float* p = Af + (size_t)(m0 + srow) * K + (tid & 3) * 8;
    p0 = *(const float4*)p;
    p1 = *(const float4*)(p + 4);
  } else {
    int r = m0 + srow, kk = scs * 8;
    gl16(Ax + (size_t)(r >> 5) * 65536 + (size_t)(kk >> 6) * 16384 +
             (t0 + (r & 31)) * 64 + (kk & 63),
         &ldsA[0][tid * 8]);
  }
#pragma unroll
  for (int i = 0; i < 2; i++) {
    int idx = i * 512 + tid, brow = idx >> 2;
    int bcs = (idx & 3) ^ (brow & 3);
    gl16(Bt + (size_t)(n0 + brow) * K + bcs * 8, &ldsB[0][idx * 8]);
  }
  if (AMODE == 0) {
    *(ushort4*)&ldsA[0][aslot]     = ushort4{f2bf(p0.x), f2bf(p0.y), f2bf(p0.z), f2bf(p0.w)};
    *(ushort4*)&ldsA[0][aslot + 4] = ushort4{f2bf(p1.x), f2bf(p1.y), f2bf(p1.z), f2bf(p1.w)};
  }
  __syncthreads();

  int cur = 0;
  for (int k0 = 0; k0 < K; k0 += 32) {
    const int kn = k0 + 32;
    const bool more = kn < K;
    float4 q0, q1;
    if (more) {
      if (AMODE == 0) {
        const float* p = Af + (size_t)(m0 + srow) * K + kn + (tid & 3) * 8;
        q0 = *(const float4*)p;
        q1 = *(const float4*)(p + 4);
      } else {
        int r = m0 + srow, kk = kn + scs * 8;
        gl16(Ax + (size_t)(r >> 5) * 65536 + (size_t)(kk >> 6) * 16384 +
                 (t0 + (r & 31)) * 64 + (kk & 63),
             &ldsA[cur ^ 1][tid * 8]);
      }
#pragma unroll
      for (int i = 0; i < 2; i++) {
        int idx = i * 512 + tid, brow = idx >> 2;
        int bcs = (idx & 3) ^ (brow & 3);
        gl16(Bt + (size_t)(n0 + brow) * K + kn + bcs * 8, &ldsB[cur ^ 1][idx * 8]);
      }
    }
    bf16x8 a[4], b[4];
#pragma unroll
    for (int i = 0; i < 4; i++)
      a[i] = *(const bf16x8*)&ldsA[cur][(wm * 64 + i * 16 + l16) * 32 + xsw];
#pragma unroll
    for (int j = 0; j < 4; j++)
      b[j] = *(const bf16x8*)&ldsB[cur][(wn * 64 + j * 16 + l16) * 32 + xsw];
#pragma unroll
    for (int i = 0; i < 4; i++)
#pragma unroll
      for (int j = 0; j < 4; j++)
        acc[i][j] = __builtin_amdgcn_mfma_f32_16x16x32_bf16(a[i], b[j], acc[i][j], 0, 0, 0);
    if (AMODE == 0 && more) {
      *(ushort4*)&ldsA[cur ^ 1][aslot]     = ushort4{f2bf(q0.x), f2bf(q0.y), f2bf(q0.z), f2bf(q0.w)};
      *(ushort4*)&ldsA[cur ^ 1][aslot + 4] = ushort4{f2bf(q1.x), f2bf(q1.y), f2bf(q1.z), f2bf(q1.w)};
    }
    __syncthreads();
    cur ^= 1;
  }

  if (STORE_T) {
    // per-wave LDS transpose -> 128B-contiguous runs along tt per column
    const int nseg = m0 >> 8;
    const int ttw  = (m0 & 255) + wm * 64;    // wave's tt base (64 rows)
    const int col16 = lane >> 2, part = lane & 3;
    u16* xwp = &xw[w * 16 * 70];
#pragma unroll
    for (int j = 0; j < 4; j++) {
      int col = n0 + wn * 64 + j * 16 + l16;
      float bv = bias[col];
#pragma unroll
      for (int i = 0; i < 4; i++)
#pragma unroll
        for (int r = 0; r < 4; r++) {
          float v = acc[i][j][r] + bv;
          if (RELU) v = fmaxf(v, 0.f);
          xwp[l16 * 70 + i * 16 + quad * 4 + r] = f2bf(v);
        }
      // read transposed (within-wave; compiler orders ds_write->ds_read)
      u16x8 v0 = *(const u16x8*)&xwp[col16 * 70 + part * 16];
      u16x8 v1 = *(const u16x8*)&xwp[col16 * 70 + part * 16 + 8];
      int colS = n0 + wn * 64 + j * 16 + col16;
      size_t ob = (size_t)nseg * 65536 + (size_t)(colS >> 6) * 16384 +
                  (size_t)(colS & 63) * 256 + ttw + part * 16;
      *(u16x8*)&out[ob]     = v0;
      *(u16x8*)&out[ob + 8] = v1;
    }
  } else {
#pragma unroll
    for (int j = 0; j < 4; j++) {
      int col = n0 + wn * 64 + j * 16 + l16;
      float bv = bias[col];
#pragma unroll
      for (int i = 0; i < 4; i++) {
        int row0 = m0 + wm * 64 + i * 16 + quad * 4;
#pragma unroll
        for (int r = 0; r < 4; r++) {
          float v = acc[i][j][r] + bv;
          if (RELU) v = fmaxf(v, 0.f);
          out[(size_t)(row0 + r) * Nld + col] = f2bf(v);
        }
      }
    }
  }
}

// ---------------- K2: attention (in-place on xac) ----------------
// Round-7 fix: ldsC staged via global_load_lds with CONTIGUOUS source
// (id*16B; was lane=f at 512B stride -> 4x L3 over-fetch ~512MB/dispatch,
// the reason attn was pinned at ~113us). Layout [f 64][slot 32][8] with
// slot = tchunk ^ (f&7) (source-side XOR; reads swizzle to match).
__global__ __launch_bounds__(256, 3) void k_attn(
    u16* xac,
    const u16* __restrict__ Wt,       // attn_w^T: [t'][t] 256x256
    const float* __restrict__ attn_b) {
  __shared__ __attribute__((aligned(16))) u16 ldsC[16384];  // [f][slot][8] swizzled
  __shared__ float redmax[4][64];
  __shared__ float redsum[4][64];
  __shared__ __attribute__((aligned(16))) u16 xbuf[4][16][76];  // per-wave transpose
  const int tid  = threadIdx.x;
  const int w    = tid >> 6;
  const int lane = tid & 63;
  const int quad = lane >> 4;
  const int l16  = lane & 15;
  const int seg = blockIdx.x;
  const int c4  = blockIdx.y;
  u16* reg = xac + (size_t)seg * 65536 + (size_t)c4 * 16384;

  // staging: contiguous global 16B chunks, source pre-swizzled, linear LDS dest
#pragma unroll
  for (int u = 0; u < 8; u++) {
    int id = u * 256 + tid;          // (f = id>>5, tchunk = id&31)
    int f = id >> 5;
    gl16(reg + ((id * 8) ^ ((f & 7) << 3)), &ldsC[id * 8]);
  }
  __syncthreads();   // vmcnt drained -> ldsC ready

  f32x4 acc[4][4];
#pragma unroll
  for (int i = 0; i < 4; i++)
#pragma unroll
    for (int j = 0; j < 4; j++) acc[i][j] = f32x4{0.f, 0.f, 0.f, 0.f};

#pragma unroll
  for (int s = 0; s < 8; s++) {
    int k0 = s * 32;
    bf16x8 a[4], b[4];
#pragma unroll
    for (int i = 0; i < 4; i++)
      a[i] = *(const bf16x8*)(Wt + (size_t)(w * 64 + i * 16 + l16) * 256 + k0 + quad * 8);
#pragma unroll
    for (int j = 0; j < 4; j++) {
      int fl = j * 16 + l16;
      b[j] = *(const bf16x8*)&ldsC[(fl * 256 + s * 32 + quad * 8) ^ ((fl & 7) << 3)];
    }
#pragma unroll
    for (int i = 0; i < 4; i++)
#pragma unroll
      for (int j = 0; j < 4; j++)
        acc[i][j] = __builtin_amdgcn_mfma_f32_16x16x32_bf16(a[i], b[j], acc[i][j], 0, 0, 0);
  }

#pragma unroll
  for (int i = 0; i < 4; i++)
#pragma unroll
    for (int r = 0; r < 4; r++) {
      float ab = attn_b[w * 64 + i * 16 + quad * 4 + r];
#pragma unroll
      for (int j = 0; j < 4; j++) acc[i][j][r] += ab;
    }

  float lmax[4];
#pragma unroll
  for (int j = 0; j < 4; j++) {
    float m = -1e30f;
#pragma unroll
    for (int i = 0; i < 4; i++)
#pragma unroll
      for (int r = 0; r < 4; r++) m = fmaxf(m, acc[i][j][r]);
    m = fmaxf(m, __shfl_xor(m, 16));
    m = fmaxf(m, __shfl_xor(m, 32));
    lmax[j] = m;
  }
  if (quad == 0) {
#pragma unroll
    for (int j = 0; j < 4; j++) redmax[w][j * 16 + l16] = lmax[j];
  }
  __syncthreads();
  float gmax[4];
#pragma unroll
  for (int j = 0; j < 4; j++) {
    int c = j * 16 + l16;
    gmax[j] = fmaxf(fmaxf(redmax[0][c], redmax[1][c]), fmaxf(redmax[2][c], redmax[3][c]));
  }
  float lsum[4];
#pragma unroll
  for (int j = 0; j < 4; j++) {
    float sacc = 0.f;
#pragma unroll
    for (int i = 0; i < 4; i++)
#pragma unroll
      for (int r = 0; r < 4; r++) {
        float e = __expf(acc[i][j][r] - gmax[j]);
        acc[i][j][r] = e;
        sacc += e;
      }
    sacc += __shfl_xor(sacc, 16);
    sacc += __shfl_xor(sacc, 32);
    lsum[j] = sacc;
  }
  if (quad == 0) {
#pragma unroll
    for (int j = 0; j < 4; j++) redsum[w][j * 16 + l16] = lsum[j];
  }
  __syncthreads();
  float rinv[4];
#pragma unroll
  for (int j = 0; j < 4; j++) {
    int c = j * 16 + l16;
    rinv[j] = 1.0f / (redsum[0][c] + redsum[1][c] + redsum[2][c] + redsum[3][c]);
  }

  // epilogue: per-wave LDS transpose -> 16B coalesced stores (t-major x_att)
#pragma unroll
  for (int i = 0; i < 4; i++) {
#pragma unroll
    for (int r = 0; r < 4; r++) {
      int tp = w * 64 + i * 16 + quad * 4 + r;
#pragma unroll
      for (int j = 0; j < 4; j++) {
        int fl = j * 16 + l16;
        float cv = bf2f(ldsC[(fl * 256 + tp) ^ ((fl & 7) << 3)]);
        float xa = acc[i][j][r] * rinv[j] * cv;
        xbuf[w][quad * 4 + r][fl] = f2bf(xa);   // within-wave buffer
      }
    }
    int rr = lane >> 2, oc = lane & 3;
    u16x8 v0 = *(const u16x8*)&xbuf[w][rr][oc * 16];
    u16x8 v1 = *(const u16x8*)&xbuf[w][rr][oc * 16 + 8];
    int tpb = w * 64 + i * 16 + rr;
    *(u16x8*)&reg[(size_t)tpb * 64 + oc * 16]     = v0;
    *(u16x8*)&reg[(size_t)tpb * 64 + oc * 16 + 8] = v1;
  }
}

// ---------------- K4: GRU scan, register-resident U (round-6, unchanged) ----------------
__global__ __launch_bounds__(512) __attribute__((amdgpu_waves_per_eu(2, 2)))
void k_scan(
    const u16* __restrict__ gc,   // gates chunk [NSEG*TC][768] (x@W + bi)
    const u16* __restrict__ Ut,   // gru_u^T [768][256]
    const float* __restrict__ br, // gru_b[1]: [768]
    float* __restrict__ hio,      // [NSEG][256] fp32 (d_out)
    int init) {
  __shared__ __attribute__((aligned(16))) u16 hbT[2][4096];   // [s][quad][seg][e]
  __shared__ __attribute__((aligned(16))) u16 ldsG[2][12288]; // [g][cg][r][quad][l16]
  const int tid  = threadIdx.x;
  const int w    = tid >> 6;
  const int lane = tid & 63;
  const int quad = lane >> 4;
  const int l16  = lane & 15;
  const int n0 = blockIdx.x * 16;
  const int cg[2] = {w, 8 + w};   // two col-groups per wave (per gate)

  // ALL Ut fragments register-resident: [grp][gate][s], 48 x bf16x8 = 192 VGPR
  bf16x8 U[2][3][8];
#pragma unroll
  for (int grp = 0; grp < 2; grp++)
#pragma unroll
    for (int g = 0; g < 3; g++)
#pragma unroll
      for (int s = 0; s < 8; s++) {
        U[grp][g][s] = *(const bf16x8*)(Ut + (size_t)(g * 256 + cg[grp] * 16 + l16) * 256 + s * 32 + quad * 8);
        asm volatile("" : "+v"(U[grp][g][s]));   // pin: no remat, must stay live
      }

  float brZ[2], brR[2], brH[2];
#pragma unroll
  for (int grp = 0; grp < 2; grp++) {
    int c = cg[grp] * 16 + l16;
    brZ[grp] = br[c]; brR[grp] = br[256 + c]; brH[grp] = br[512 + c];
  }

  // uniform-per-thread index bases
  int gbase[2], hwb[2];
#pragma unroll
  for (int grp = 0; grp < 2; grp++) {
    gbase[grp] = cg[grp] * 256 + quad * 16 + l16;           // + g*4096 + r*64
    int c = cg[grp] * 16 + l16;
    hwb[grp] = (c >> 5) * 512 + ((c >> 3) & 3) * 128 + (c & 7) + quad * 32;  // + r*8
  }
  const int ahb = quad * 128 + l16 * 8;                     // + s*512

  // h init: registers + hbT[0]
  float hreg[2][4];
#pragma unroll
  for (int grp = 0; grp < 2; grp++)
#pragma unroll
    for (int r = 0; r < 4; r++) {
      hreg[grp][r] = init ? 0.f
                          : hio[(size_t)(n0 + quad * 4 + r) * 256 + cg[grp] * 16 + l16];
      hbT[0][hwb[grp] + r * 8] = f2bf(hreg[grp][r]);
    }

  // gate staging: this thread's 3 chunks (id = tid + k*512), permuted source
  const u16* sp[3];
#pragma unroll
  for (int k = 0; k < 3; k++) {
    int id = tid + k * 512;
    int a = id & 1, q = (id >> 1) & 3, r = (id >> 3) & 3;
    int cgv = (id >> 5) & 15, g = id >> 9;
    sp[k] = gc + ((size_t)(n0 + q * 4 + r) * 32 + 0) * 768 + g * 256 + cgv * 16 + a * 8;
  }
  // prologue: stage tt=0 into ldsG[0]
#pragma unroll
  for (int k = 0; k < 3; k++) {
    gl16(sp[k], &ldsG[0][(tid + k * 512) * 8]);
    sp[k] += 768;   // now points at tt=1
  }
  __syncthreads();   // hbT[0] visible; vmcnt drained -> ldsG[0] ready

  for (int tt = 0; tt < TC; tt++) {
    // stage next step's gates (consumed after next barrier)
    if (tt + 1 < TC) {
#pragma unroll
      for (int k = 0; k < 3; k++) {
        gl16(sp[k], &ldsG[(tt + 1) & 1][(tid + k * 512) * 8]);
        sp[k] += 768;
      }
    }

    f32x4 acc[2][3];
#pragma unroll
    for (int grp = 0; grp < 2; grp++)
#pragma unroll
      for (int g = 0; g < 3; g++) acc[grp][g] = f32x4{0.f, 0.f, 0.f, 0.f};

    const u16* hR = hbT[tt & 1];
#pragma unroll
    for (int s = 0; s < 8; s++) {
      bf16x8 ah = *(const bf16x8*)&hR[ahb + s * 512];   // contiguous 1KB span: conflict-free
#pragma unroll
      for (int grp = 0; grp < 2; grp++)
#pragma unroll
        for (int g = 0; g < 3; g++)
          acc[grp][g] = __builtin_amdgcn_mfma_f32_16x16x32_bf16(ah, U[grp][g][s], acc[grp][g], 0, 0, 0);
    }

    const u16* G = ldsG[tt & 1];
    u16* hW = hbT[(tt + 1) & 1];
#pragma unroll
    for (int grp = 0; grp < 2; grp++)
#pragma unroll
      for (int r = 0; r < 4; r++) {
        float gz = bf2f(G[gbase[grp] + 0 * 4096 + r * 64]);
        float gr = bf2f(G[gbase[grp] + 1 * 4096 + r * 64]);
        float gh = bf2f(G[gbase[grp] + 2 * 4096 + r * 64]);
        float z  = sigm(acc[grp][0][r] + gz + brZ[grp]);
        float rg = sigm(acc[grp][1][r] + gr + brR[grp]);
        float hh = fmaxf(gh + rg * (acc[grp][2][r] + brH[grp]), 0.f);
        float hn = z * hreg[grp][r] + (1.0f - z) * hh;
        hreg[grp][r] = hn;
        hW[hwb[grp] + r * 8] = f2bf(hn);
      }
    __syncthreads();   // hW visible; hR reads retired; next gates landed (vmcnt)
  }

#pragma unroll
  for (int grp = 0; grp < 2; grp++)
#pragma unroll
    for (int r = 0; r < 4; r++)
      hio[(size_t)(n0 + quad * 4 + r) * 256 + cg[grp] * 16 + l16] = hreg[grp][r];
}

// ---------------- host ----------------
extern "C" void kernel_launch(void* const* d_in, const int* in_sizes, int n_in,
                              void* d_out, int out_size, void* d_ws, size_t ws_size,
                              hipStream_t stream) {
  (void)in_sizes; (void)n_in; (void)out_size;
  const float* x      = (const float*)d_in[0];
  const float* conv_w = (const float*)d_in[1];
  const float* conv_b = (const float*)d_in[2];
  const float* attn_w = (const float*)d_in[3];
  const float* attn_b = (const float*)d_in[4];
  const float* gru_w  = (const float*)d_in[5];
  const float* gru_u  = (const float*)d_in[6];
  const float* gru_b  = (const float*)d_in[7];

  // scratch layout: 185,532,416 B total (known-safe: < 202,309,696 proven)
  const size_t NEEDED = 185532416;
  if (ws_size < NEEDED) return;
  char* ws = (char*)d_ws;
  u16* xac     = (u16*)(ws);                  // 134217728 B: convT then x_att (chunked, in-place)
  u16* gatesC  = (u16*)(ws + 134217728);      //  50331648 B: gates for one 32-step chunk
  u16* conv_wT = (u16*)(ws + 184549376);      //     65536 B [f][c]
  u16* attn_wT = (u16*)(ws + 184614912);      //    131072 B [t'][t]
  u16* gru_wT  = (u16*)(ws + 184745984);      //    393216 B [j][f]
  u16* gru_uT  = (u16*)(ws + 185139200);      //    393216 B [j][k]

  hipLaunchKernelGGL(k_transp4, dim3(1920), dim3(256), 0, stream,
                     conv_w, attn_w, gru_w, gru_u, conv_wT, attn_wT, gru_wT, gru_uT);

  // K1: conv = relu(x @ conv_w + b); full N=256 per block -> fp32 A read ONCE
  hipLaunchKernelGGL((k_gemm<true, true, 0>), dim3(2048, 1), dim3(512), 0, stream,
                     (const void*)x, conv_wT, conv_b, xac, 128, 0, 0);
  // K2: attention softmax + multiply, in place on xac
  hipLaunchKernelGGL(k_attn, dim3(1024, 4), dim3(256), 0, stream,
                     xac, attn_wT, attn_b);
  // K3/K4: 8 time chunks of (gates GEMM -> 32-step scan); h lives in d_out
  for (int c = 0; c < 8; c++) {
    hipLaunchKernelGGL((k_gemm<false, false, 1>), dim3(256, 3), dim3(512), 0, stream,
                       (const void*)xac, gru_wT, gru_b, gatesC, 256, 768, c * TC);
    hipLaunchKernelGGL(k_scan, dim3(64), dim3(512), 0, stream,
                       gatesC, gru_uT, gru_b + 768, (float*)d_out, c == 0 ? 1 : 0);
  }
}